// Round 1
// baseline (1082.635 us; speedup 1.0000x reference)
//
#include <hip/hip_runtime.h>

#define B 64
#define SIZE 2048
#define L 16
#define A 64
#define HID 256
#define R_N 65536
#define XCOLS (SIZE + L)
#define D2A 128
#define D3A 192

#define ST_ELEMS ((L + 1) * SIZE * B)
#define REL_ELEMS (R_N * A)

// ---------------- init: ST[0] = init^T, ST[1..16] = 0 ----------------
__global__ __launch_bounds__(256) void k_init(const int* __restrict__ x,
                                              float* __restrict__ ST) {
    int total = ST_ELEMS;
    for (int idx = blockIdx.x * blockDim.x + threadIdx.x; idx < total;
         idx += gridDim.x * blockDim.x) {
        if (idx < SIZE * B) {
            int s = idx >> 6, b = idx & 63;
            ST[idx] = (float)x[b * XCOLS + s];
        } else {
            ST[idx] = 0.f;
        }
    }
}

// ---------------- relation = relu(rel_in@w1+b1)@w2+b2 ----------------
// one block = 16 relations
__global__ __launch_bounds__(256) void k_relation(
    const int* __restrict__ rel_subj, const int* __restrict__ rel_obj,
    const float* __restrict__ state_emb, const float* __restrict__ w1,
    const float* __restrict__ b1, const float* __restrict__ w2,
    const float* __restrict__ b2, float* __restrict__ relation) {
    __shared__ float rin[16][128];
    __shared__ float hid[16][HID];
    int tid = threadIdx.x;
    int r0 = blockIdx.x * 16;

    for (int i = tid; i < 16 * 128; i += 256) {
        int r = i >> 7, k = i & 127;
        int idx = (k < 64) ? rel_subj[r0 + r] : rel_obj[r0 + r];
        rin[r][k] = state_emb[idx * 64 + (k & 63)];
    }
    __syncthreads();

    // hidden: thread tid = hidden unit j, 16 relations per thread
    float acc[16];
    float bb = b1[tid];
#pragma unroll
    for (int r = 0; r < 16; r++) acc[r] = bb;
    for (int k = 0; k < 128; k++) {
        float w = w1[k * HID + tid];
#pragma unroll
        for (int r = 0; r < 16; r++) acc[r] += rin[r][k] * w;
    }
#pragma unroll
    for (int r = 0; r < 16; r++) hid[r][tid] = fmaxf(acc[r], 0.f);
    __syncthreads();

    // out: c = tid&63 output col, rg = tid>>6 handles 4 relations
    int c = tid & 63, rg = tid >> 6;
    float acc2[4];
    float bb2 = b2[c];
#pragma unroll
    for (int rr = 0; rr < 4; rr++) acc2[rr] = bb2;
    for (int k = 0; k < HID; k++) {
        float w = w2[k * 64 + c];
#pragma unroll
        for (int rr = 0; rr < 4; rr++) acc2[rr] += hid[rg * 4 + rr][k] * w;
    }
#pragma unroll
    for (int rr = 0; rr < 4; rr++)
        relation[(size_t)(r0 + rg * 4 + rr) * 64 + c] = acc2[rr];
}

// ---------------- meta chain: one block per batch, 16 steps ----------------
__global__ __launch_bounds__(256) void k_meta(
    const int* __restrict__ x, const float* __restrict__ action_emb,
    const float* __restrict__ pos_emb, const float* __restrict__ q_w,
    const float* __restrict__ q_b, const float* __restrict__ ms_w1,
    const float* __restrict__ ms_b1, const float* __restrict__ ms_w2,
    const float* __restrict__ ms_b2, const float* __restrict__ meta_init,
    float* __restrict__ metas) {
    __shared__ float sent[L][D2A];
    __shared__ float meta_s[A];
    __shared__ float query_s[D2A];
    __shared__ float logits_s[L];
    __shared__ float attn_s[L];
    __shared__ float catv[D3A];
    __shared__ float hidden_s[HID];
    __shared__ float red[L][8];
    __shared__ float part2[4][A];
    int tid = threadIdx.x;
    int b = blockIdx.x;

    for (int i = tid; i < L * D2A; i += 256) {
        int l = i >> 7, d = i & 127;
        float v;
        if (d < 64) {
            int act = x[b * XCOLS + SIZE + l];
            v = action_emb[act * 64 + d];
        } else {
            v = pos_emb[l * 64 + (d - 64)];
        }
        sent[l][d] = v;
    }
    if (tid < A) meta_s[tid] = meta_init[tid];
    __syncthreads();

    for (int t = 0; t < L; t++) {
        // query = meta @ q_w + q_b
        if (tid < D2A) {
            float q = q_b[tid];
            for (int k = 0; k < A; k++) q += meta_s[k] * q_w[k * D2A + tid];
            query_s[tid] = q;
        }
        __syncthreads();
        // logits
        if (tid < 128) {
            int l = tid >> 3, sub = tid & 7;
            float p = 0.f;
            for (int d = sub; d < D2A; d += 8) p += query_s[d] * sent[l][d];
            red[l][sub] = p;
        }
        __syncthreads();
        if (tid < L) {
            float s = 0.f;
#pragma unroll
            for (int j = 0; j < 8; j++) s += red[tid][j];
            logits_s[tid] = s;
        }
        __syncthreads();
        if (tid < L) {
            float mx = -1e30f;
            for (int l = 0; l < L; l++) mx = fmaxf(mx, logits_s[l]);
            float sum = 0.f;
            for (int l = 0; l < L; l++) sum += __expf(logits_s[l] - mx);
            attn_s[tid] = __expf(logits_s[tid] - mx) / sum;
        }
        __syncthreads();
        // attended + cat = [meta, attended]
        if (tid < D2A) {
            float a = 0.f;
#pragma unroll
            for (int l = 0; l < L; l++) a += attn_s[l] * sent[l][tid];
            catv[A + tid] = a;
        } else if (tid < D2A + A) {
            catv[tid - D2A] = meta_s[tid - D2A];
        }
        __syncthreads();
        // hidden = relu(cat @ ms_w1 + b1)
        {
            float h = ms_b1[tid];
            for (int k = 0; k < D3A; k++) h += catv[k] * ms_w1[k * HID + tid];
            hidden_s[tid] = fmaxf(h, 0.f);
        }
        __syncthreads();
        // new meta = hidden @ ms_w2 + b2 (split-k over 4 waves)
        {
            int c = tid & 63, kg = tid >> 6;
            float p = 0.f;
            for (int k = kg * 64; k < kg * 64 + 64; k++)
                p += hidden_s[k] * ms_w2[k * 64 + c];
            part2[kg][c] = p;
        }
        __syncthreads();
        if (tid < A) {
            float nm = ms_b2[tid] + part2[0][tid] + part2[1][tid] +
                       part2[2][tid] + part2[3][tid];
            meta_s[tid] = nm;
            metas[((size_t)t * B + b) * A + tid] = nm;
        }
        __syncthreads();
    }
}

// ---------------- one state step: h=sigmoid(meta@rel^T); scatter ----------------
// 256 blocks x 256 threads; block handles 256 relations; lane = batch
__global__ __launch_bounds__(256) void k_step(
    const int* __restrict__ rel_subj, const int* __restrict__ rel_obj,
    const float* __restrict__ relation, const float* __restrict__ metas,
    const float* __restrict__ st_in, float* __restrict__ st_out, int t) {
    __shared__ float rel_lds[64][64];
    int tid = threadIdx.x;
    int lane = tid & 63;
    int wave = tid >> 6;

    float4 m[16];
    const float4* mp = (const float4*)(metas + ((size_t)t * B + lane) * A);
#pragma unroll
    for (int i = 0; i < 16; i++) m[i] = mp[i];

    int rbase = blockIdx.x * 256;
    for (int chunk = 0; chunk < 4; chunk++) {
        int r0 = rbase + chunk * 64;
        __syncthreads();
        for (int i = tid; i < 64 * 16; i += 256) {
            ((float4*)rel_lds)[i] = ((const float4*)(relation + (size_t)r0 * 64))[i];
        }
        __syncthreads();
        for (int rr = wave; rr < 64; rr += 4) {
            const float4* rp = (const float4*)rel_lds[rr];
            float acc = 0.f;
#pragma unroll
            for (int i = 0; i < 16; i++) {
                float4 rv = rp[i];
                acc += m[i].x * rv.x + m[i].y * rv.y + m[i].z * rv.z +
                       m[i].w * rv.w;
            }
            float h = 1.f / (1.f + __expf(-acc));
            int r = r0 + rr;
            int subj = rel_subj[r];
            int obj = rel_obj[r];
            float val = st_in[(size_t)subj * B + lane] * h;
            atomicAdd(&st_out[(size_t)obj * B + lane], val);
        }
    }
}

// ---------------- final transpose: out[b][t][s] = ST[t+1][s][b] ----------------
__global__ __launch_bounds__(256) void k_out(const float* __restrict__ ST,
                                             float* __restrict__ out) {
    __shared__ float tile[64][65];
    int t = blockIdx.x >> 5;
    int s0 = (blockIdx.x & 31) * 64;
    const float* src = ST + (size_t)(t + 1) * SIZE * B;
    int tid = threadIdx.x;
    for (int i = tid; i < 64 * 64; i += 256) {
        int si = i >> 6, b = i & 63;
        tile[si][b] = src[(size_t)(s0 + si) * B + b];
    }
    __syncthreads();
    for (int i = tid; i < 64 * 64; i += 256) {
        int b = i >> 6, si = i & 63;
        out[((size_t)b * L + t) * SIZE + s0 + si] = tile[si][b];
    }
}

extern "C" void kernel_launch(void* const* d_in, const int* in_sizes, int n_in,
                              void* d_out, int out_size, void* d_ws,
                              size_t ws_size, hipStream_t stream) {
    const int* x = (const int*)d_in[0];
    const int* rel_subj = (const int*)d_in[1];
    const int* rel_obj = (const int*)d_in[2];
    const float* action_emb = (const float*)d_in[3];
    const float* pos_emb = (const float*)d_in[4];
    const float* state_emb = (const float*)d_in[5];
    const float* s2r_w1 = (const float*)d_in[6];
    const float* s2r_b1 = (const float*)d_in[7];
    const float* s2r_w2 = (const float*)d_in[8];
    const float* s2r_b2 = (const float*)d_in[9];
    const float* q_w = (const float*)d_in[10];
    const float* q_b = (const float*)d_in[11];
    const float* ms_w1 = (const float*)d_in[12];
    const float* ms_b1 = (const float*)d_in[13];
    const float* ms_w2 = (const float*)d_in[14];
    const float* ms_b2 = (const float*)d_in[15];
    const float* meta_init = (const float*)d_in[16];

    float* ws = (float*)d_ws;
    float* ST = ws;
    float* relation = ws + ST_ELEMS;
    float* metas = relation + REL_ELEMS;
    float* out = (float*)d_out;

    k_init<<<1024, 256, 0, stream>>>(x, ST);
    k_relation<<<R_N / 16, 256, 0, stream>>>(rel_subj, rel_obj, state_emb,
                                             s2r_w1, s2r_b1, s2r_w2, s2r_b2,
                                             relation);
    k_meta<<<B, 256, 0, stream>>>(x, action_emb, pos_emb, q_w, q_b, ms_w1,
                                  ms_b1, ms_w2, ms_b2, meta_init, metas);
    for (int t = 0; t < L; t++) {
        k_step<<<256, 256, 0, stream>>>(rel_subj, rel_obj, relation, metas,
                                        ST + (size_t)t * SIZE * B,
                                        ST + (size_t)(t + 1) * SIZE * B, t);
    }
    k_out<<<512, 256, 0, stream>>>(ST, out);
}

// Round 2
// 766.965 us; speedup vs baseline: 1.4116x; 1.4116x over previous
//
#include <hip/hip_runtime.h>

#define B 64
#define SIZE 2048
#define L 16
#define A 64
#define HID 256
#define R_N 65536
#define XCOLS (SIZE + L)

#define ST_ELEMS ((L + 1) * SIZE * B)

__device__ __forceinline__ float bflo(unsigned int u) {
    return __uint_as_float(u << 16);
}
__device__ __forceinline__ float bfhi(unsigned int u) {
    return __uint_as_float(u & 0xffff0000u);
}
__device__ __forceinline__ unsigned short f2bf(float f) {
    unsigned int u = __float_as_uint(f);
    unsigned int r = (u + 0x7fffu + ((u >> 16) & 1u)) >> 16;
    return (unsigned short)r;
}

// ---------- init: ST[0] = x[:, :SIZE]^T (tiles), plus zero hist/cursor ----------
__global__ __launch_bounds__(256) void k_init(const int* __restrict__ x,
                                              float* __restrict__ ST,
                                              int* __restrict__ hist,
                                              int* __restrict__ cursor) {
    int tid = threadIdx.x;
    if (blockIdx.x == 32) {
        for (int i = tid; i < 2048; i += 256) {
            hist[i] = 0;
            cursor[i] = 0;
        }
        return;
    }
    __shared__ float tile[64][65];
    int s0 = blockIdx.x * 64;
    for (int i = tid; i < 4096; i += 256) {
        int b = i >> 6, sc = i & 63;
        tile[b][sc] = (float)x[b * XCOLS + s0 + sc];
    }
    __syncthreads();
    for (int i = tid; i < 4096; i += 256) {
        int si = i >> 6, b = i & 63;
        ST[(size_t)(s0 + si) * B + b] = tile[b][si];
    }
}

// ---------- histogram of rel_obj ----------
__global__ __launch_bounds__(256) void k_hist(const int* __restrict__ rel_obj,
                                              int* __restrict__ hist) {
    for (int i = blockIdx.x * 256 + threadIdx.x; i < R_N; i += 64 * 256)
        atomicAdd(&hist[rel_obj[i]], 1);
}

// ---------- exclusive scan (2048 bins), single block ----------
__global__ __launch_bounds__(256) void k_scan(const int* __restrict__ hist,
                                              int* __restrict__ off) {
    __shared__ int tsum[256];
    int tid = threadIdx.x;
    int v[8], pre[8];
    int s = 0;
#pragma unroll
    for (int i = 0; i < 8; i++) {
        v[i] = hist[tid * 8 + i];
        pre[i] = s;
        s += v[i];
    }
    tsum[tid] = s;
    __syncthreads();
    for (int ofs = 1; ofs < 256; ofs <<= 1) {
        int t = 0;
        if (tid >= ofs) t = tsum[tid - ofs];
        __syncthreads();
        tsum[tid] += t;
        __syncthreads();
    }
    int ebase = tsum[tid] - s;
#pragma unroll
    for (int i = 0; i < 8; i++) off[tid * 8 + i] = ebase + pre[i];
    if (tid == 255) off[2048] = tsum[255];
}

// ---------- scatter sorted positions ----------
__global__ __launch_bounds__(256) void k_scatter(const int* __restrict__ rel_subj,
                                                 const int* __restrict__ rel_obj,
                                                 const int* __restrict__ off,
                                                 int* __restrict__ cursor,
                                                 int* __restrict__ subjS,
                                                 int* __restrict__ objS) {
    for (int r = blockIdx.x * 256 + threadIdx.x; r < R_N; r += 64 * 256) {
        int obj = rel_obj[r];
        int pos = off[obj] + atomicAdd(&cursor[obj], 1);
        subjS[pos] = rel_subj[r];
        objS[pos] = obj;
    }
}

// ---------- P1 = emb @ W1a, P2 = emb @ W1b ----------
__global__ __launch_bounds__(256) void k_p12(const float* __restrict__ state_emb,
                                             const float* __restrict__ w1,
                                             float* __restrict__ P1,
                                             float* __restrict__ P2) {
    __shared__ float emb8[8][64];
    int tid = threadIdx.x;
    int sbase = blockIdx.x * 8;
    for (int i = tid; i < 512; i += 256)
        emb8[i >> 6][i & 63] = state_emb[(size_t)(sbase + (i >> 6)) * 64 + (i & 63)];
    __syncthreads();
    float acc1[8], acc2[8];
#pragma unroll
    for (int s = 0; s < 8; s++) { acc1[s] = 0.f; acc2[s] = 0.f; }
    for (int k = 0; k < 64; k++) {
        float wa = w1[(size_t)k * HID + tid];
        float wb = w1[(size_t)(64 + k) * HID + tid];
#pragma unroll
        for (int s = 0; s < 8; s++) {
            acc1[s] += emb8[s][k] * wa;
            acc2[s] += emb8[s][k] * wb;
        }
    }
#pragma unroll
    for (int s = 0; s < 8; s++) {
        P1[(size_t)(sbase + s) * HID + tid] = acc1[s];
        P2[(size_t)(sbase + s) * HID + tid] = acc2[s];
    }
}

// ---------- relS[i] = bf16( relu(P1[subj]+P2[obj]+b1) @ w2 + b2 ), sorted order ----------
__global__ __launch_bounds__(256) void k_rel2(const int* __restrict__ subjS,
                                              const int* __restrict__ objS,
                                              const float* __restrict__ P1,
                                              const float* __restrict__ P2,
                                              const float* __restrict__ b1,
                                              const float* __restrict__ w2,
                                              const float* __restrict__ b2,
                                              unsigned short* __restrict__ relS) {
    __shared__ unsigned short h4[64 * HID];  // bf16 hidden, 32 KB
    __shared__ int subj_l[64], obj_l[64];
    int tid = threadIdx.x;
    int rbase = blockIdx.x * 64;
    if (tid < 64) {
        subj_l[tid] = subjS[rbase + tid];
        obj_l[tid] = objS[rbase + tid];
    }
    __syncthreads();
    // stage hidden (bf16)
    for (int e = tid; e < 64 * 64; e += 256) {
        int r = e >> 6, jc = e & 63;
        const float4 p1 = *(const float4*)&P1[(size_t)subj_l[r] * HID + jc * 4];
        const float4 p2 = *(const float4*)&P2[(size_t)obj_l[r] * HID + jc * 4];
        const float4 bv = *(const float4*)&b1[jc * 4];
        ushort4 hv;
        hv.x = f2bf(fmaxf(p1.x + p2.x + bv.x, 0.f));
        hv.y = f2bf(fmaxf(p1.y + p2.y + bv.y, 0.f));
        hv.z = f2bf(fmaxf(p1.z + p2.z + bv.z, 0.f));
        hv.w = f2bf(fmaxf(p1.w + p2.w + bv.w, 0.f));
        ((ushort4*)h4)[r * 64 + jc] = hv;
    }
    __syncthreads();
    // GEMM2: 64x64, K=256
    int c = tid & 63, rg = tid >> 6;
    float acc[16];
#pragma unroll
    for (int r = 0; r < 16; r++) acc[r] = 0.f;
    for (int j4 = 0; j4 < 64; j4++) {
        float w0 = w2[(size_t)(j4 * 4 + 0) * 64 + c];
        float w1v = w2[(size_t)(j4 * 4 + 1) * 64 + c];
        float w2v = w2[(size_t)(j4 * 4 + 2) * 64 + c];
        float w3 = w2[(size_t)(j4 * 4 + 3) * 64 + c];
#pragma unroll
        for (int r = 0; r < 16; r++) {
            ushort4 hv = ((ushort4*)h4)[(rg * 16 + r) * 64 + j4];
            acc[r] += bflo(hv.x) * w0 + bflo(hv.y) * w1v + bflo(hv.z) * w2v +
                      bflo(hv.w) * w3;
        }
    }
    float b2v = b2[c];
#pragma unroll
    for (int r = 0; r < 16; r++)
        relS[(size_t)(rbase + rg * 16 + r) * 64 + c] = f2bf(acc[r] + b2v);
}

// ---------- meta chain: folded algebra, weights in registers ----------
__global__ __launch_bounds__(256) void k_meta(
    const int* __restrict__ x, const float* __restrict__ action_emb,
    const float* __restrict__ pos_emb, const float* __restrict__ q_w,
    const float* __restrict__ q_b, const float* __restrict__ ms_w1,
    const float* __restrict__ ms_b1, const float* __restrict__ ms_w2,
    const float* __restrict__ ms_b2, const float* __restrict__ meta_init,
    float* __restrict__ metas) {
    __shared__ float sent[L][128];
    __shared__ float meta_lds[A];
    __shared__ float logits_lds[L];
    __shared__ float qb_lds[L];
    __shared__ float hidden_lds[HID];
    __shared__ float parts[4][A];
    __shared__ float b2_lds[A];
    int tid = threadIdx.x;
    int b = blockIdx.x;

    for (int i = tid; i < L * 128; i += 256) {
        int l = i >> 7, d = i & 127;
        float v;
        if (d < 64) {
            int act = x[b * XCOLS + SIZE + l];
            v = action_emb[act * 64 + d];
        } else {
            v = pos_emb[l * 64 + (d - 64)];
        }
        sent[l][d] = v;
    }
    if (tid < A) {
        meta_lds[tid] = meta_init[tid];
        b2_lds[tid] = ms_b2[tid];
    }
    __syncthreads();

    // ---- one-time precompute into registers ----
    // W1a column (tid = hidden unit j)
    float w1a_r[64];
#pragma unroll
    for (int k = 0; k < 64; k++) w1a_r[k] = ms_w1[(size_t)k * HID + tid];
    // sentW row: sentw_r[l] = sum_d sent[l][d] * ms_w1[64+d][tid]
    float sentw_r[16];
#pragma unroll
    for (int l = 0; l < 16; l++) sentw_r[l] = 0.f;
    for (int d = 0; d < 128; d++) {
        float w = ms_w1[(size_t)(64 + d) * HID + tid];
#pragma unroll
        for (int l = 0; l < 16; l++) sentw_r[l] += sent[l][d] * w;
    }
    // w2 column chunk (c = tid&63, kg = tid>>6)
    int c = tid & 63, kg = tid >> 6;
    float w2_r[64];
#pragma unroll
    for (int i = 0; i < 64; i++) w2_r[i] = ms_w2[(size_t)(kg * 64 + i) * 64 + c];
    // qs registers: thread (l_q = tid>>4, sub = tid&15) holds qs[sub*4+i][l_q]
    int l_q = tid >> 4, sub = tid & 15;
    float qs_r[4];
#pragma unroll
    for (int i = 0; i < 4; i++) {
        int k = sub * 4 + i;
        float a = 0.f;
#pragma unroll 8
        for (int j = 0; j < 128; j++) a += q_w[(size_t)k * 128 + j] * sent[l_q][j];
        qs_r[i] = a;
    }
    if (tid < 16) {
        float a = 0.f;
        for (int j = 0; j < 128; j++) a += q_b[j] * sent[tid][j];
        qb_lds[tid] = a;
    }
    float b1r = ms_b1[tid];
    __syncthreads();

    // ---- 16 steps, 4 barriers each ----
    for (int t = 0; t < L; t++) {
        // logits[l] = sum_k meta[k]*qs[k][l] + qb[l]
        float p = 0.f;
#pragma unroll
        for (int i = 0; i < 4; i++) p += meta_lds[sub * 4 + i] * qs_r[i];
        p += __shfl_xor(p, 8);
        p += __shfl_xor(p, 4);
        p += __shfl_xor(p, 2);
        p += __shfl_xor(p, 1);
        if (sub == 0) logits_lds[l_q] = p + qb_lds[l_q];
        __syncthreads();
        // hidden[j] = relu(b1 + meta@W1a[:,j] + attn@sentW[:,j])
        float mx = logits_lds[0];
#pragma unroll
        for (int l = 1; l < 16; l++) mx = fmaxf(mx, logits_lds[l]);
        float attn[16];
        float se = 0.f;
#pragma unroll
        for (int l = 0; l < 16; l++) {
            attn[l] = __expf(logits_lds[l] - mx);
            se += attn[l];
        }
        float inv = 1.f / se;
        float h = b1r;
#pragma unroll
        for (int k = 0; k < 64; k++) h += meta_lds[k] * w1a_r[k];
#pragma unroll
        for (int l = 0; l < 16; l++) h += attn[l] * inv * sentw_r[l];
        hidden_lds[tid] = fmaxf(h, 0.f);
        __syncthreads();
        // meta2 split-k
        float pp = 0.f;
#pragma unroll
        for (int i = 0; i < 64; i++) pp += hidden_lds[kg * 64 + i] * w2_r[i];
        parts[kg][c] = pp;
        __syncthreads();
        if (tid < A) {
            float nm = b2_lds[tid] + parts[0][tid] + parts[1][tid] +
                       parts[2][tid] + parts[3][tid];
            meta_lds[tid] = nm;
            metas[((size_t)t * B + b) * A + tid] = nm;
        }
        __syncthreads();
    }
}

// ---------- state step: sorted relations, no atomics ----------
// grid 1024; block = 2 objs; obj gets 2 waves (half-buckets); lane = batch
__global__ __launch_bounds__(256) void k_step(const int* __restrict__ off,
                                              const int* __restrict__ subjS,
                                              const unsigned short* __restrict__ relS,
                                              const float* __restrict__ metas,
                                              const float* __restrict__ st_in,
                                              float* __restrict__ st_out, int t) {
    __shared__ float acc_lds[4][64];
    int tid = threadIdx.x;
    int lane = tid & 63;
    int w = tid >> 6;
    int obj = blockIdx.x * 2 + (w >> 1);
    int half = w & 1;

    float4 m[16];
    const float4* mp = (const float4*)(metas + ((size_t)t * B + lane) * A);
#pragma unroll
    for (int i = 0; i < 16; i++) m[i] = mp[i];

    int beg = off[obj], end = off[obj + 1];
    float acc = 0.f;
    for (int i = beg + half; i < end; i += 2) {
        int subj = subjS[i];
        const uint4* rp = (const uint4*)(relS + (size_t)i * 64);
        float4 a0 = {0.f, 0.f, 0.f, 0.f}, a1 = {0.f, 0.f, 0.f, 0.f};
#pragma unroll
        for (int q = 0; q < 8; q++) {
            uint4 u = rp[q];
            float4 m0 = m[2 * q], m1 = m[2 * q + 1];
            a0.x += m0.x * bflo(u.x);
            a0.y += m0.y * bfhi(u.x);
            a0.z += m0.z * bflo(u.y);
            a0.w += m0.w * bfhi(u.y);
            a1.x += m1.x * bflo(u.z);
            a1.y += m1.y * bfhi(u.z);
            a1.z += m1.z * bflo(u.w);
            a1.w += m1.w * bfhi(u.w);
        }
        float dot = (a0.x + a0.y + a0.z + a0.w) + (a1.x + a1.y + a1.z + a1.w);
        float hs = 1.f / (1.f + __expf(-dot));
        acc += st_in[(size_t)subj * B + lane] * hs;
    }
    acc_lds[w][lane] = acc;
    __syncthreads();
    if (tid < 128) {
        int o = tid >> 6, ln = tid & 63;
        float v = acc_lds[o * 2][ln] + acc_lds[o * 2 + 1][ln];
        st_out[(size_t)(blockIdx.x * 2 + o) * B + ln] = v;
    }
}

// ---------- final transpose ----------
__global__ __launch_bounds__(256) void k_out(const float* __restrict__ ST,
                                             float* __restrict__ out) {
    __shared__ float tile[64][65];
    int t = blockIdx.x >> 5;
    int s0 = (blockIdx.x & 31) * 64;
    const float* src = ST + (size_t)(t + 1) * SIZE * B;
    int tid = threadIdx.x;
    for (int i = tid; i < 64 * 64; i += 256) {
        int si = i >> 6, b = i & 63;
        tile[si][b] = src[(size_t)(s0 + si) * B + b];
    }
    __syncthreads();
    for (int i = tid; i < 64 * 64; i += 256) {
        int b = i >> 6, si = i & 63;
        out[((size_t)b * L + t) * SIZE + s0 + si] = tile[si][b];
    }
}

extern "C" void kernel_launch(void* const* d_in, const int* in_sizes, int n_in,
                              void* d_out, int out_size, void* d_ws,
                              size_t ws_size, hipStream_t stream) {
    const int* x = (const int*)d_in[0];
    const int* rel_subj = (const int*)d_in[1];
    const int* rel_obj = (const int*)d_in[2];
    const float* action_emb = (const float*)d_in[3];
    const float* pos_emb = (const float*)d_in[4];
    const float* state_emb = (const float*)d_in[5];
    const float* s2r_w1 = (const float*)d_in[6];
    const float* s2r_b1 = (const float*)d_in[7];
    const float* s2r_w2 = (const float*)d_in[8];
    const float* s2r_b2 = (const float*)d_in[9];
    const float* q_w = (const float*)d_in[10];
    const float* q_b = (const float*)d_in[11];
    const float* ms_w1 = (const float*)d_in[12];
    const float* ms_b1 = (const float*)d_in[13];
    const float* ms_w2 = (const float*)d_in[14];
    const float* ms_b2 = (const float*)d_in[15];
    const float* meta_init = (const float*)d_in[16];

    float* ws = (float*)d_ws;
    float* ST = ws;                                   // 2228224 f
    unsigned short* relS = (unsigned short*)(ws + ST_ELEMS);  // 4194304 us
    float* metas = ws + ST_ELEMS + R_N * 64 / 2;      // 65536 f
    float* P1 = metas + L * B * A;                    // 524288 f
    float* P2 = P1 + SIZE * HID;                      // 524288 f
    int* ibase = (int*)(P2 + SIZE * HID);
    int* hist = ibase;          // 2048
    int* off = ibase + 2048;    // 2049
    int* cursor = off + 2049;   // 2048
    int* subjS = cursor + 2048; // 65536
    int* objS = subjS + R_N;    // 65536
    float* out = (float*)d_out;

    k_init<<<33, 256, 0, stream>>>(x, ST, hist, cursor);
    k_hist<<<64, 256, 0, stream>>>(rel_obj, hist);
    k_scan<<<1, 256, 0, stream>>>(hist, off);
    k_scatter<<<64, 256, 0, stream>>>(rel_subj, rel_obj, off, cursor, subjS, objS);
    k_p12<<<SIZE / 8, 256, 0, stream>>>(state_emb, s2r_w1, P1, P2);
    k_rel2<<<R_N / 64, 256, 0, stream>>>(subjS, objS, P1, P2, s2r_b1, s2r_w2,
                                         s2r_b2, relS);
    k_meta<<<B, 256, 0, stream>>>(x, action_emb, pos_emb, q_w, q_b, ms_w1,
                                  ms_b1, ms_w2, ms_b2, meta_init, metas);
    for (int t = 0; t < L; t++) {
        k_step<<<1024, 256, 0, stream>>>(off, subjS, relS, metas,
                                         ST + (size_t)t * SIZE * B,
                                         ST + (size_t)(t + 1) * SIZE * B, t);
    }
    k_out<<<512, 256, 0, stream>>>(ST, out);
}